// Round 1
// baseline (6815.385 us; speedup 1.0000x reference)
//
#include <hip/hip_runtime.h>
#include <math.h>

#define N 4096
#define DIM 64
#define MAX_ITER 50
#define EPS 0.1f
#define INV_EPS 10.0f
#define THRESH 0.1f

// ---------------- init: zero u, v, err_arr in workspace ----------------
__global__ void init_ws(float* __restrict__ ws) {
    int i = blockIdx.x * 256 + threadIdx.x;
    if (i < 2 * N + MAX_ITER) ws[i] = 0.0f;
}

// ---------------- build D[i][j] = sum_d (A[i][d]-B[j][d])^2 ----------------
// grid (64,64), block 256. 64x64 tile per block, 4x4 micro-tile per thread.
__global__ __launch_bounds__(256) void build_dist(const float* __restrict__ A,
                                                  const float* __restrict__ B,
                                                  float* __restrict__ Dst) {
    __shared__ float As[64][68];
    __shared__ float Bs[64][68];
    const int i0 = blockIdx.y << 6, j0 = blockIdx.x << 6;
    const int t = threadIdx.x;
    const float* Ag = A + (size_t)i0 * DIM;
    const float* Bg = B + (size_t)j0 * DIM;
    // 64 rows x 64 dims = 4096 contiguous floats per tile (row-major input)
    for (int k = t; k < 4096; k += 256) {
        As[k >> 6][k & 63] = Ag[k];
        Bs[k >> 6][k & 63] = Bg[k];
    }
    __syncthreads();
    const int ty = t >> 4, tx = t & 15;
    float acc[4][4] = {{0.f}};
    for (int d = 0; d < DIM; d += 4) {
        float4 av[4], bv[4];
#pragma unroll
        for (int a = 0; a < 4; ++a) av[a] = *(const float4*)&As[ty + 16 * a][d];
#pragma unroll
        for (int b = 0; b < 4; ++b) bv[b] = *(const float4*)&Bs[tx + 16 * b][d];
#pragma unroll
        for (int a = 0; a < 4; ++a)
#pragma unroll
            for (int b = 0; b < 4; ++b) {
                float d0 = av[a].x - bv[b].x;
                float d1 = av[a].y - bv[b].y;
                float d2 = av[a].z - bv[b].z;
                float d3 = av[a].w - bv[b].w;
                acc[a][b] = fmaf(d0, d0, acc[a][b]);
                acc[a][b] = fmaf(d1, d1, acc[a][b]);
                acc[a][b] = fmaf(d2, d2, acc[a][b]);
                acc[a][b] = fmaf(d3, d3, acc[a][b]);
            }
    }
#pragma unroll
    for (int a = 0; a < 4; ++a) {
        int i = i0 + ty + 16 * a;
        float* drow = Dst + (size_t)i * N + j0;
#pragma unroll
        for (int b = 0; b < 4; ++b) drow[tx + 16 * b] = acc[a][b];
    }
}

// ---------------- one Sinkhorn half-step ----------------
// u_new_i = target - EPS * LSE_j((other_j - Mtx[i][j]) * INV_EPS)
// One block per row. Emulates reference freeze: skip if any err_arr[0..iter-1] < THRESH.
__global__ __launch_bounds__(256, 4) void sinkhorn_phase(
    const float* __restrict__ Mtx, const float* __restrict__ other,
    float* __restrict__ mine, float* __restrict__ err_arr, int iter,
    int write_err, float target) {
    const int t = threadIdx.x;
    // done-check: lanes 0..49 of every wave read err history in parallel (uniform result)
    {
        int lane = t & 63;
        bool conv = (lane < iter) && (err_arr[lane] < THRESH);
        if (__ballot(conv) != 0ull) return;
    }
    const int row = blockIdx.x;
    const float* __restrict__ rowp = Mtx + (size_t)row * N;
    float tv[16];
#pragma unroll
    for (int k = 0; k < 16; ++k) {
        int j = t + 256 * k;
        tv[k] = (other[j] - rowp[j]) * INV_EPS;
    }
    // block max
    float m = tv[0];
#pragma unroll
    for (int k = 1; k < 16; ++k) m = fmaxf(m, tv[k]);
#pragma unroll
    for (int off = 32; off; off >>= 1) m = fmaxf(m, __shfl_xor(m, off));
    __shared__ float red[8];
    if ((t & 63) == 0) red[t >> 6] = m;
    __syncthreads();
    m = fmaxf(fmaxf(red[0], red[1]), fmaxf(red[2], red[3]));
    // block sum of exp
    float s = 0.f;
#pragma unroll
    for (int k = 0; k < 16; ++k) s += __expf(tv[k] - m);
#pragma unroll
    for (int off = 32; off; off >>= 1) s += __shfl_xor(s, off);
    if ((t & 63) == 0) red[4 + (t >> 6)] = s;
    __syncthreads();
    if (t == 0) {
        s = red[4] + red[5] + red[6] + red[7];
        float lse = m + __logf(s);
        float un = target - EPS * lse;
        if (write_err) atomicAdd(&err_arr[iter], fabsf(un - mine[row]));
        mine[row] = un;
    }
}

// ---------------- zero the cost slot (after Ct scratch is dead) ----------------
__global__ void zero_one(float* p) { *p = 0.0f; }

// ---------------- final: pi = exp((u_i + v_j - C)/eps), cost = sum(pi*C) ----------------
__global__ __launch_bounds__(256, 4) void sinkhorn_final(
    const float* __restrict__ Cm, const float* __restrict__ u,
    const float* __restrict__ v, float* __restrict__ pi,
    float* __restrict__ cost) {
    const int row = blockIdx.x;
    const int t = threadIdx.x;
    const float* __restrict__ rowp = Cm + (size_t)row * N;
    float* __restrict__ pip = pi + (size_t)row * N;
    const float ui = u[row];
    float csum = 0.f;
#pragma unroll
    for (int k = 0; k < 16; ++k) {
        int j = t + 256 * k;
        float c = rowp[j];
        float p = __expf((ui + v[j] - c) * INV_EPS);
        pip[j] = p;
        csum = fmaf(p, c, csum);
    }
#pragma unroll
    for (int off = 32; off; off >>= 1) csum += __shfl_xor(csum, off);
    __shared__ float red[4];
    if ((t & 63) == 0) red[t >> 6] = csum;
    __syncthreads();
    if (t == 0) atomicAdd(cost, red[0] + red[1] + red[2] + red[3]);
}

extern "C" void kernel_launch(void* const* d_in, const int* in_sizes, int n_in,
                              void* d_out, int out_size, void* d_ws, size_t ws_size,
                              hipStream_t stream) {
    const float* x = (const float*)d_in[0];  // [4096,64]
    const float* y = (const float*)d_in[1];  // [4096,64]
    float* out = (float*)d_out;              // [0]=cost, [1..N*N]=pi, [1+N*N..]=C
    float* pi = out + 1;
    float* C = out + 1 + (size_t)N * N;
    float* Ct = out;  // scratch: aliases cost+pi region, dead until final pass
    float* ws = (float*)d_ws;
    float* u = ws;
    float* v = ws + N;
    float* err = ws + 2 * N;  // err_arr[MAX_ITER]

    init_ws<<<dim3((2 * N + MAX_ITER + 255) / 256), dim3(256), 0, stream>>>(ws);

    dim3 bgrid(64, 64);
    build_dist<<<bgrid, dim3(256), 0, stream>>>(x, y, C);   // C[i][j]
    build_dist<<<bgrid, dim3(256), 0, stream>>>(y, x, Ct);  // C^T[j][i]

    float log_mu = logf(1.0f / (float)N + 1e-8f);  // == log_nu (P1==P2)
    float target = EPS * log_mu;

    for (int it = 0; it < MAX_ITER; ++it) {
        // u-update: row LSE over C with v
        sinkhorn_phase<<<dim3(N), dim3(256), 0, stream>>>(C, v, u, err, it, 1, target);
        // v-update: row LSE over C^T with (new) u
        sinkhorn_phase<<<dim3(N), dim3(256), 0, stream>>>(Ct, u, v, err, it, 0, target);
    }

    zero_one<<<dim3(1), dim3(1), 0, stream>>>(out);
    sinkhorn_final<<<dim3(N), dim3(256), 0, stream>>>(C, u, v, pi, out);
}

// Round 2
// 3805.501 us; speedup vs baseline: 1.7909x; 1.7909x over previous
//
#include <hip/hip_runtime.h>
#include <math.h>

#define N 4096
#define DIM 64
#define MAX_ITER 50
#define EPS 0.1f
#define INV_EPS 10.0f
#define THRESH 0.1f

// ---------------- init: zero u, v, err_arr in workspace ----------------
__global__ void init_ws(float* __restrict__ ws) {
    int i = blockIdx.x * 256 + threadIdx.x;
    if (i < 2 * N + MAX_ITER) ws[i] = 0.0f;
}

// ---------------- build D[i][j] = sum_d (A[i][d]-B[j][d])^2 ----------------
// grid (64,64), block 256. 64x64 tile per block, 4x4 micro-tile per thread.
__global__ __launch_bounds__(256) void build_dist(const float* __restrict__ A,
                                                  const float* __restrict__ B,
                                                  float* __restrict__ Dst) {
    __shared__ float As[64][68];
    __shared__ float Bs[64][68];
    const int i0 = blockIdx.y << 6, j0 = blockIdx.x << 6;
    const int t = threadIdx.x;
    const float* Ag = A + (size_t)i0 * DIM;
    const float* Bg = B + (size_t)j0 * DIM;
    for (int k = t; k < 4096; k += 256) {
        As[k >> 6][k & 63] = Ag[k];
        Bs[k >> 6][k & 63] = Bg[k];
    }
    __syncthreads();
    const int ty = t >> 4, tx = t & 15;
    float acc[4][4] = {{0.f}};
    for (int d = 0; d < DIM; d += 4) {
        float4 av[4], bv[4];
#pragma unroll
        for (int a = 0; a < 4; ++a) av[a] = *(const float4*)&As[ty + 16 * a][d];
#pragma unroll
        for (int b = 0; b < 4; ++b) bv[b] = *(const float4*)&Bs[tx + 16 * b][d];
#pragma unroll
        for (int a = 0; a < 4; ++a)
#pragma unroll
            for (int b = 0; b < 4; ++b) {
                float d0 = av[a].x - bv[b].x;
                float d1 = av[a].y - bv[b].y;
                float d2 = av[a].z - bv[b].z;
                float d3 = av[a].w - bv[b].w;
                acc[a][b] = fmaf(d0, d0, acc[a][b]);
                acc[a][b] = fmaf(d1, d1, acc[a][b]);
                acc[a][b] = fmaf(d2, d2, acc[a][b]);
                acc[a][b] = fmaf(d3, d3, acc[a][b]);
            }
    }
#pragma unroll
    for (int a = 0; a < 4; ++a) {
        int i = i0 + ty + 16 * a;
        float* drow = Dst + (size_t)i * N + j0;
#pragma unroll
        for (int b = 0; b < 4; ++b) drow[tx + 16 * b] = acc[a][b];
    }
}

// ---------------- one Sinkhorn half-step, 2 rows per block ----------------
// u_new_i = target - max_j(v_j - C_ij) - EPS*log(sum_j exp((d_j - dmax)*INV_EPS))
// All loads are float4 held in registers: 12 independent 16B/lane loads in
// flight per thread (8 C + 4 v) -> latency hidden by MLP, not just TLP.
__global__ __launch_bounds__(256) void sinkhorn_phase(
    const float* __restrict__ Mtx, const float* __restrict__ other,
    float* __restrict__ mine, float* __restrict__ err_arr, int iter,
    int write_err, float target) {
    const int t = threadIdx.x;
    // emulate reference's data-dependent freeze (uniform across block)
    {
        int lane = t & 63;
        bool conv = (lane < iter) && (err_arr[lane] < THRESH);
        if (__ballot(conv) != 0ull) return;
    }
    const int r0 = blockIdx.x * 2;
    const float4* __restrict__ row0 = (const float4*)(Mtx + (size_t)r0 * N);
    const float4* __restrict__ row1 = (const float4*)(Mtx + (size_t)(r0 + 1) * N);
    const float4* __restrict__ vv = (const float4*)other;
    float4 C0[4], C1[4], V[4];
#pragma unroll
    for (int k = 0; k < 4; ++k) {
        const int f = t + 256 * k;  // float4 index 0..1023, lane-consecutive
        C0[k] = row0[f];
        C1[k] = row1[f];
        V[k] = vv[f];
    }
    // per-thread max of d = v - c (scale by INV_EPS afterwards; monotone)
    float m0 = -1e30f, m1 = -1e30f;
#pragma unroll
    for (int k = 0; k < 4; ++k) {
        m0 = fmaxf(m0, fmaxf(fmaxf(V[k].x - C0[k].x, V[k].y - C0[k].y),
                             fmaxf(V[k].z - C0[k].z, V[k].w - C0[k].w)));
        m1 = fmaxf(m1, fmaxf(fmaxf(V[k].x - C1[k].x, V[k].y - C1[k].y),
                             fmaxf(V[k].z - C1[k].z, V[k].w - C1[k].w)));
    }
#pragma unroll
    for (int off = 32; off; off >>= 1) {
        m0 = fmaxf(m0, __shfl_xor(m0, off));
        m1 = fmaxf(m1, __shfl_xor(m1, off));
    }
    __shared__ float red[8];
    if ((t & 63) == 0) {
        red[t >> 6] = m0;
        red[4 + (t >> 6)] = m1;
    }
    __syncthreads();
    m0 = fmaxf(fmaxf(red[0], red[1]), fmaxf(red[2], red[3]));
    m1 = fmaxf(fmaxf(red[4], red[5]), fmaxf(red[6], red[7]));
    __syncthreads();  // red reused below
    // sum of exp
    float s0 = 0.f, s1 = 0.f;
#pragma unroll
    for (int k = 0; k < 4; ++k) {
        s0 += __expf((V[k].x - C0[k].x - m0) * INV_EPS);
        s0 += __expf((V[k].y - C0[k].y - m0) * INV_EPS);
        s0 += __expf((V[k].z - C0[k].z - m0) * INV_EPS);
        s0 += __expf((V[k].w - C0[k].w - m0) * INV_EPS);
        s1 += __expf((V[k].x - C1[k].x - m1) * INV_EPS);
        s1 += __expf((V[k].y - C1[k].y - m1) * INV_EPS);
        s1 += __expf((V[k].z - C1[k].z - m1) * INV_EPS);
        s1 += __expf((V[k].w - C1[k].w - m1) * INV_EPS);
    }
#pragma unroll
    for (int off = 32; off; off >>= 1) {
        s0 += __shfl_xor(s0, off);
        s1 += __shfl_xor(s1, off);
    }
    if ((t & 63) == 0) {
        red[t >> 6] = s0;
        red[4 + (t >> 6)] = s1;
    }
    __syncthreads();
    if (t == 0) {
        s0 = red[0] + red[1] + red[2] + red[3];
        s1 = red[4] + red[5] + red[6] + red[7];
        // u_new = target - EPS*(m*INV_EPS + log s) = target - m - EPS*log s
        float un0 = target - m0 - EPS * __logf(s0);
        float un1 = target - m1 - EPS * __logf(s1);
        if (write_err)
            atomicAdd(&err_arr[iter],
                      fabsf(un0 - mine[r0]) + fabsf(un1 - mine[r0 + 1]));
        mine[r0] = un0;
        mine[r0 + 1] = un1;
    }
}

// ---------------- zero the cost slot (after Ct scratch is dead) ----------------
__global__ void zero_one(float* p) { *p = 0.0f; }

// ---------------- final: pi = exp((u_i + v_j - C)/eps), cost = sum(pi*C) ----------------
__global__ __launch_bounds__(256) void sinkhorn_final(
    const float* __restrict__ Cm, const float* __restrict__ u,
    const float* __restrict__ v, float* __restrict__ pi,
    float* __restrict__ cost) {
    const int row = blockIdx.x;
    const int t = threadIdx.x;
    const float4* __restrict__ rowp = (const float4*)(Cm + (size_t)row * N);
    float4* __restrict__ pip = (float4*)(pi + (size_t)row * N);
    const float4* __restrict__ vv = (const float4*)v;
    const float ui = u[row];
    float csum = 0.f;
#pragma unroll
    for (int k = 0; k < 4; ++k) {
        const int f = t + 256 * k;
        float4 c = rowp[f];
        float4 w = vv[f];
        float4 p;
        p.x = __expf((ui + w.x - c.x) * INV_EPS);
        p.y = __expf((ui + w.y - c.y) * INV_EPS);
        p.z = __expf((ui + w.z - c.z) * INV_EPS);
        p.w = __expf((ui + w.w - c.w) * INV_EPS);
        pip[f] = p;
        csum = fmaf(p.x, c.x, csum);
        csum = fmaf(p.y, c.y, csum);
        csum = fmaf(p.z, c.z, csum);
        csum = fmaf(p.w, c.w, csum);
    }
#pragma unroll
    for (int off = 32; off; off >>= 1) csum += __shfl_xor(csum, off);
    __shared__ float red[4];
    if ((t & 63) == 0) red[t >> 6] = csum;
    __syncthreads();
    if (t == 0) atomicAdd(cost, red[0] + red[1] + red[2] + red[3]);
}

extern "C" void kernel_launch(void* const* d_in, const int* in_sizes, int n_in,
                              void* d_out, int out_size, void* d_ws, size_t ws_size,
                              hipStream_t stream) {
    const float* x = (const float*)d_in[0];  // [4096,64]
    const float* y = (const float*)d_in[1];  // [4096,64]
    float* out = (float*)d_out;              // [0]=cost, [1..N*N]=pi, [1+N*N..]=C
    float* pi = out + 1;
    float* C = out + 1 + (size_t)N * N;
    float* Ct = out;  // scratch: aliases cost+pi region, dead until final pass
    float* ws = (float*)d_ws;
    float* u = ws;
    float* v = ws + N;
    float* err = ws + 2 * N;  // err_arr[MAX_ITER]

    init_ws<<<dim3((2 * N + MAX_ITER + 255) / 256), dim3(256), 0, stream>>>(ws);

    dim3 bgrid(64, 64);
    build_dist<<<bgrid, dim3(256), 0, stream>>>(x, y, C);   // C[i][j]
    build_dist<<<bgrid, dim3(256), 0, stream>>>(y, x, Ct);  // C^T[j][i]

    float log_mu = logf(1.0f / (float)N + 1e-8f);  // == log_nu (P1==P2)
    float target = EPS * log_mu;

    for (int it = 0; it < MAX_ITER; ++it) {
        sinkhorn_phase<<<dim3(N / 2), dim3(256), 0, stream>>>(C, v, u, err, it, 1, target);
        sinkhorn_phase<<<dim3(N / 2), dim3(256), 0, stream>>>(Ct, u, v, err, it, 0, target);
    }

    zero_one<<<dim3(1), dim3(1), 0, stream>>>(out);
    sinkhorn_final<<<dim3(N), dim3(256), 0, stream>>>(C, u, v, pi, out);
}